// Round 1
// baseline (374.020 us; speedup 1.0000x reference)
//
#include <hip/hip_runtime.h>

// B=2, S=2048, IN_F=1024, HEADS=8, DPH=64, OUT_F=1024.
// Quirk: reshape is a raw view -> per (b,h) the Q/K/V matrices are CONTIGUOUS
// [2048,64] slabs of the [4096,512] projection output at offset bh*131072.
// Quirk: no pre-softmax scale; divide by 8 AFTER softmax (folded into O epilogue).

using short8  = __attribute__((ext_vector_type(8))) short;
using short4v = __attribute__((ext_vector_type(4))) short;
using f32x4   = __attribute__((ext_vector_type(4))) float;
using float4v = __attribute__((ext_vector_type(4))) float;
using uint4v  = __attribute__((ext_vector_type(4))) unsigned int;

__device__ __forceinline__ unsigned short f2bf(float x) {
  unsigned int u = __float_as_uint(x);
  u += 0x7FFFu + ((u >> 16) & 1u);          // round-to-nearest-even
  return (unsigned short)(u >> 16);
}

// ---------------- f32 -> bf16 convert (4 elems/thread) ----------------
__global__ __launch_bounds__(256) void k_cvt(const float* __restrict__ in,
                                             unsigned short* __restrict__ out,
                                             int n4) {
  int id = blockIdx.x * 256 + threadIdx.x;
  if (id >= n4) return;
  float4v v = *(const float4v*)(in + (size_t)id * 4);
  short4v o;
#pragma unroll
  for (int i = 0; i < 4; ++i) o[i] = (short)f2bf(v[i]);
  *(short4v*)(out + (size_t)id * 4) = o;
}

// ---------------- W[K,N] f32 -> WT[N,K] bf16 (write-coalesced) ----------------
__global__ __launch_bounds__(256) void k_twt(const float* __restrict__ W,
                                             unsigned short* __restrict__ WT,
                                             int K, int N) {
  int id = blockIdx.x * 256 + threadIdx.x;   // id = n*K + k
  if (id >= K * N) return;
  int n = id / K, k = id - n * K;
  WT[id] = f2bf(W[(size_t)k * N + n]);
}

// ---------------- V[4096,512] bf16 -> VT[bh][64][2048] bf16 ----------------
__global__ __launch_bounds__(256) void k_tv(const unsigned short* __restrict__ V,
                                            unsigned short* __restrict__ VT) {
  int id = blockIdx.x * 256 + threadIdx.x;   // 2,097,152 total, exact grid
  int s = id >> 9, c = id & 511;
  int b = s >> 11, sl = s & 2047;
  int h = sl >> 8;
  int r = ((sl & 255) << 3) | (c >> 6);
  int d = c & 63;
  VT[(size_t)(((b << 3) | h) * 64 + d) * 2048 + r] = V[id];
}

// ---------------- bf16 GEMM: C[M,N] = A[M,K] @ BT[N,K]^T, bf16 out ----------------
__global__ __launch_bounds__(256) void k_gemm(const unsigned short* __restrict__ A,
                                              const unsigned short* __restrict__ BT,
                                              unsigned short* __restrict__ C,
                                              int M, int N, int K) {
  __shared__ alignas(16) unsigned short As[64][72];   // +8 pad: 144B stride, 16B aligned
  __shared__ alignas(16) unsigned short Bs[64][72];
  const int tid = threadIdx.x, w = tid >> 6, l = tid & 63;
  const int lr = l & 15, lg = l >> 4;
  const int m0 = blockIdx.x * 64, n0 = blockIdx.y * 64;
  f32x4 acc[4] = {};
  for (int k0 = 0; k0 < K; k0 += 64) {
#pragma unroll
    for (int c = tid; c < 512; c += 256) {
      int row = c >> 3, cc = c & 7;
      *(uint4v*)&As[row][cc * 8] = *(const uint4v*)&A[(size_t)(m0 + row) * K + k0 + cc * 8];
      *(uint4v*)&Bs[row][cc * 8] = *(const uint4v*)&BT[(size_t)(n0 + row) * K + k0 + cc * 8];
    }
    __syncthreads();
#pragma unroll
    for (int kk = 0; kk < 64; kk += 32) {
      short8 a = *(const short8*)&As[w * 16 + lr][kk + lg * 8];
#pragma unroll
      for (int f = 0; f < 4; ++f) {
        short8 b = *(const short8*)&Bs[f * 16 + lr][kk + lg * 8];
        acc[f] = __builtin_amdgcn_mfma_f32_16x16x32_bf16(a, b, acc[f], 0, 0, 0);
      }
    }
    __syncthreads();
  }
#pragma unroll
  for (int f = 0; f < 4; ++f)
#pragma unroll
    for (int r = 0; r < 4; ++r)
      C[(size_t)(m0 + w * 16 + lg * 4 + r) * N + n0 + f * 16 + lr] = f2bf(acc[f][r]);
}

// ---------------- flash attention over contiguous [2048,64] heads ----------------
__global__ __launch_bounds__(256) void k_attn(const unsigned short* __restrict__ Qb,
                                              const unsigned short* __restrict__ Kb,
                                              const unsigned short* __restrict__ VT,
                                              unsigned short* __restrict__ ctx) {
  __shared__ alignas(16) unsigned short Plds[4][16][72];  // per-wave P bounce
  const int tid = threadIdx.x, w = tid >> 6, l = tid & 63;
  const int lr = l & 15, lg = l >> 4;
  const int bh = blockIdx.y;
  const int q0 = blockIdx.x * 64;
  const unsigned short* Qh  = Qb + (size_t)bh * 131072;   // [2048][64]
  const unsigned short* Kh  = Kb + (size_t)bh * 131072;   // [2048][64]
  const unsigned short* VTh = VT + (size_t)bh * 131072;   // [64][2048]
  const int qrow = q0 + w * 16;

  short8 qa0 = *(const short8*)&Qh[(size_t)(qrow + lr) * 64 + lg * 8];
  short8 qa1 = *(const short8*)&Qh[(size_t)(qrow + lr) * 64 + 32 + lg * 8];

  f32x4 O[4] = {};
  float m_i[4] = {-1e30f, -1e30f, -1e30f, -1e30f};
  float l_i[4] = {0.f, 0.f, 0.f, 0.f};

  for (int k0 = 0; k0 < 2048; k0 += 64) {
    // ---- S tile [16 q x 64 k] = Q @ K^T ----
    f32x4 s[4] = {};
#pragma unroll
    for (int t = 0; t < 4; ++t) {
      const unsigned short* krow = &Kh[(size_t)(k0 + t * 16 + lr) * 64 + lg * 8];
      short8 b0 = *(const short8*)krow;
      short8 b1 = *(const short8*)(krow + 32);
      s[t] = __builtin_amdgcn_mfma_f32_16x16x32_bf16(qa0, b0, s[t], 0, 0, 0);
      s[t] = __builtin_amdgcn_mfma_f32_16x16x32_bf16(qa1, b1, s[t], 0, 0, 0);
    }
    // ---- online softmax (row stats across the 16-lane group) ----
    float p[4][4];
#pragma unroll
    for (int r = 0; r < 4; ++r) {
      float tm = fmaxf(fmaxf(s[0][r], s[1][r]), fmaxf(s[2][r], s[3][r]));
      tm = fmaxf(tm, __shfl_xor(tm, 1));
      tm = fmaxf(tm, __shfl_xor(tm, 2));
      tm = fmaxf(tm, __shfl_xor(tm, 4));
      tm = fmaxf(tm, __shfl_xor(tm, 8));
      float mnew  = fmaxf(m_i[r], tm);
      float alpha = __expf(m_i[r] - mnew);
      float ls = 0.f;
#pragma unroll
      for (int t = 0; t < 4; ++t) { p[t][r] = __expf(s[t][r] - mnew); ls += p[t][r]; }
      ls += __shfl_xor(ls, 1);
      ls += __shfl_xor(ls, 2);
      ls += __shfl_xor(ls, 4);
      ls += __shfl_xor(ls, 8);
      l_i[r] = l_i[r] * alpha + ls;
      m_i[r] = mnew;
#pragma unroll
      for (int f = 0; f < 4; ++f) O[f][r] *= alpha;
    }
    // ---- P (C-layout) -> LDS -> A-layout fragments ----
#pragma unroll
    for (int t = 0; t < 4; ++t)
#pragma unroll
      for (int r = 0; r < 4; ++r)
        Plds[w][lg * 4 + r][t * 16 + lr] = f2bf(p[t][r]);
    __syncthreads();
    short8 pa0 = *(const short8*)&Plds[w][lr][lg * 8];
    short8 pa1 = *(const short8*)&Plds[w][lr][32 + lg * 8];
    // ---- O += P @ V (V pre-transposed: contiguous B-fragments) ----
#pragma unroll
    for (int f = 0; f < 4; ++f) {
      const unsigned short* vrow = &VTh[(size_t)(f * 16 + lr) * 2048 + k0 + lg * 8];
      short8 v0 = *(const short8*)vrow;
      short8 v1 = *(const short8*)(vrow + 32);
      O[f] = __builtin_amdgcn_mfma_f32_16x16x32_bf16(pa0, v0, O[f], 0, 0, 0);
      O[f] = __builtin_amdgcn_mfma_f32_16x16x32_bf16(pa1, v1, O[f], 0, 0, 0);
    }
    __syncthreads();
  }
#pragma unroll
  for (int f = 0; f < 4; ++f)
#pragma unroll
    for (int r = 0; r < 4; ++r) {
      float val = O[f][r] * (0.125f / l_i[r]);   // post-softmax /8 + normalization
      ctx[(size_t)(bh * 2048 + qrow + lg * 4 + r) * 64 + f * 16 + lr] = f2bf(val);
    }
}

// ---------------- out projection: OUT[32768,1024] f32 = ctx[32768,64] @ Wo + bo ----------------
__global__ __launch_bounds__(256) void k_gemmo(const unsigned short* __restrict__ A,
                                               const unsigned short* __restrict__ BT,  // WoT[1024][64]
                                               const float* __restrict__ bias,
                                               float* __restrict__ C) {
  __shared__ alignas(16) unsigned short As[64][72];
  __shared__ alignas(16) unsigned short Bs[64][72];
  const int tid = threadIdx.x, w = tid >> 6, l = tid & 63;
  const int lr = l & 15, lg = l >> 4;
  const int m0 = blockIdx.x * 64, n0 = blockIdx.y * 64;
#pragma unroll
  for (int c = tid; c < 512; c += 256) {
    int row = c >> 3, cc = c & 7;
    *(uint4v*)&As[row][cc * 8] = *(const uint4v*)&A[(size_t)(m0 + row) * 64 + cc * 8];
    *(uint4v*)&Bs[row][cc * 8] = *(const uint4v*)&BT[(size_t)(n0 + row) * 64 + cc * 8];
  }
  __syncthreads();
  f32x4 acc[4] = {};
#pragma unroll
  for (int kk = 0; kk < 64; kk += 32) {
    short8 a = *(const short8*)&As[w * 16 + lr][kk + lg * 8];
#pragma unroll
    for (int f = 0; f < 4; ++f) {
      short8 b = *(const short8*)&Bs[f * 16 + lr][kk + lg * 8];
      acc[f] = __builtin_amdgcn_mfma_f32_16x16x32_bf16(a, b, acc[f], 0, 0, 0);
    }
  }
#pragma unroll
  for (int f = 0; f < 4; ++f)
#pragma unroll
    for (int r = 0; r < 4; ++r) {
      int col = n0 + f * 16 + lr;
      C[(size_t)(m0 + w * 16 + lg * 4 + r) * 1024 + col] = acc[f][r] + bias[col];
    }
}

extern "C" void kernel_launch(void* const* d_in, const int* in_sizes, int n_in,
                              void* d_out, int out_size, void* d_ws, size_t ws_size,
                              hipStream_t stream) {
  const float* X  = (const float*)d_in[0];
  const float* Wq = (const float*)d_in[1];
  const float* Wk = (const float*)d_in[2];
  const float* Wv = (const float*)d_in[3];
  const float* Wo = (const float*)d_in[4];
  const float* bo = (const float*)d_in[5];
  float* out = (float*)d_out;

  char* ws = (char*)d_ws;
  unsigned short* Xb  = (unsigned short*)ws; ws += 8388608;   // [4096,1024] bf16
  unsigned short* WqT = (unsigned short*)ws; ws += 1048576;   // [512,1024]
  unsigned short* WkT = (unsigned short*)ws; ws += 1048576;
  unsigned short* WvT = (unsigned short*)ws; ws += 1048576;
  unsigned short* WoT = (unsigned short*)ws; ws += 131072;    // [1024,64]
  unsigned short* Qb  = (unsigned short*)ws; ws += 4194304;   // [4096,512]
  unsigned short* Kb  = (unsigned short*)ws; ws += 4194304;
  unsigned short* Vb  = (unsigned short*)ws; ws += 4194304;
  unsigned short* VT  = (unsigned short*)ws; ws += 4194304;   // [16][64][2048]
  unsigned short* Cx  = (unsigned short*)ws; ws += 4194304;   // [32768,64]

  k_cvt<<<4096, 256, 0, stream>>>(X, Xb, 1048576);
  k_twt<<<2048, 256, 0, stream>>>(Wq, WqT, 1024, 512);
  k_twt<<<2048, 256, 0, stream>>>(Wk, WkT, 1024, 512);
  k_twt<<<2048, 256, 0, stream>>>(Wv, WvT, 1024, 512);
  k_twt<<<256, 256, 0, stream>>>(Wo, WoT, 64, 1024);

  dim3 g1(64, 8);
  k_gemm<<<g1, 256, 0, stream>>>(Xb, WqT, Qb, 4096, 512, 1024);
  k_gemm<<<g1, 256, 0, stream>>>(Xb, WkT, Kb, 4096, 512, 1024);
  k_gemm<<<g1, 256, 0, stream>>>(Xb, WvT, Vb, 4096, 512, 1024);

  k_tv<<<8192, 256, 0, stream>>>(Vb, VT);
  k_attn<<<dim3(32, 16), 256, 0, stream>>>(Qb, Kb, VT, Cx);
  k_gemmo<<<dim3(512, 16), 256, 0, stream>>>(Cx, WoT, bo, out);
}

// Round 2
// 317.068 us; speedup vs baseline: 1.1796x; 1.1796x over previous
//
#include <hip/hip_runtime.h>

// B=2, S=2048, IN_F=1024, HEADS=8, DPH=64, OUT_F=1024.
// Quirk: reshape is a raw view -> per (b,h) the Q/K/V matrices are CONTIGUOUS
// [2048,64] slabs of the [4096,512] projection output at offset bh*131072.
// Quirk: no pre-softmax scale; divide by 8 AFTER softmax (folded into O epilogue).

using short8  = __attribute__((ext_vector_type(8))) short;
using short4v = __attribute__((ext_vector_type(4))) short;
using f32x4   = __attribute__((ext_vector_type(4))) float;
using float4v = __attribute__((ext_vector_type(4))) float;
using uint4v  = __attribute__((ext_vector_type(4))) unsigned int;

__device__ __forceinline__ unsigned short f2bf(float x) {
  unsigned int u = __float_as_uint(x);
  u += 0x7FFFu + ((u >> 16) & 1u);          // round-to-nearest-even
  return (unsigned short)(u >> 16);
}

// ---------------- f32 -> bf16 convert (4 elems/thread) ----------------
__global__ __launch_bounds__(256) void k_cvt(const float* __restrict__ in,
                                             unsigned short* __restrict__ out,
                                             int n4) {
  int id = blockIdx.x * 256 + threadIdx.x;
  if (id >= n4) return;
  float4v v = *(const float4v*)(in + (size_t)id * 4);
  short4v o;
#pragma unroll
  for (int i = 0; i < 4; ++i) o[i] = (short)f2bf(v[i]);
  *(short4v*)(out + (size_t)id * 4) = o;
}

// -------- W[K,N] f32 -> WT[N,K] bf16, LDS-tiled 64x64 (coalesced both sides) --------
__global__ __launch_bounds__(256) void k_twtT(const float* __restrict__ W,
                                              unsigned short* __restrict__ WT,
                                              int K, int N) {
  __shared__ alignas(16) unsigned short t[64][72];
  const int k0 = blockIdx.x * 64, n0 = blockIdx.y * 64;
  const int kk = threadIdx.x & 63, g = (threadIdx.x >> 6) * 16;
  const float* src = W + (size_t)(k0 + kk) * N + n0 + g;
#pragma unroll
  for (int j4 = 0; j4 < 4; ++j4) {
    float4v v = *(const float4v*)(src + j4 * 4);
#pragma unroll
    for (int i = 0; i < 4; ++i) t[g + j4 * 4 + i][kk] = f2bf(v[i]);
  }
  __syncthreads();
  const int nn = threadIdx.x >> 2, kg = (threadIdx.x & 3) * 16;
  short8 o0, o1;
#pragma unroll
  for (int j = 0; j < 8; ++j) { o0[j] = t[nn][kg + j]; o1[j] = t[nn][kg + 8 + j]; }
  unsigned short* dst = WT + (size_t)(n0 + nn) * K + k0 + kg;
  *(short8*)dst = o0;
  *(short8*)(dst + 8) = o1;
}

// -------- V slab [2048,64] -> VT[bh][64][2048], LDS-tiled (coalesced both sides) --------
__global__ __launch_bounds__(256) void k_tv(const unsigned short* __restrict__ Vb,
                                            unsigned short* __restrict__ VT) {
  __shared__ alignas(16) unsigned short t[64][72];
  const int bh = blockIdx.y, r0 = blockIdx.x * 64;
  const int rr = threadIdx.x & 63, g = (threadIdx.x >> 6) * 16;
  const unsigned short* src = Vb + (size_t)bh * 131072 + (size_t)(r0 + rr) * 64 + g;
  short8 a = *(const short8*)src;
  short8 b = *(const short8*)(src + 8);
#pragma unroll
  for (int j = 0; j < 8; ++j) { t[g + j][rr] = a[j]; t[g + 8 + j][rr] = b[j]; }
  __syncthreads();
  const int d = threadIdx.x >> 2, rg = (threadIdx.x & 3) * 16;
  short8 o0, o1;
#pragma unroll
  for (int j = 0; j < 8; ++j) { o0[j] = t[d][rg + j]; o1[j] = t[d][rg + 8 + j]; }
  unsigned short* dst = VT + (size_t)(bh * 64 + d) * 2048 + r0 + rg;
  *(short8*)dst = o0;
  *(short8*)(dst + 8) = o1;
}

// ------- fused QKV GEMM: C[4096,512]x3 = Xb[4096,1024] @ {Wq,Wk,Wv}T, bf16 out -------
__global__ __launch_bounds__(256) void k_gemmqkv(const unsigned short* __restrict__ A,
                                                 const unsigned short* __restrict__ WT,
                                                 unsigned short* __restrict__ Q,
                                                 unsigned short* __restrict__ K_,
                                                 unsigned short* __restrict__ V_) {
  __shared__ alignas(16) unsigned short As[64][72];
  __shared__ alignas(16) unsigned short Bs[64][72];
  const int tid = threadIdx.x, w = tid >> 6, l = tid & 63;
  const int lr = l & 15, lg = l >> 4;
  const int which = blockIdx.y >> 3;              // 0=Q 1=K 2=V
  const int n0 = (blockIdx.y & 7) * 64;
  const int m0 = blockIdx.x * 64;
  const unsigned short* BT = WT + (size_t)which * 524288;   // [512][1024] section
  unsigned short* C = (which == 0) ? Q : (which == 1) ? K_ : V_;
  f32x4 acc[4] = {};
  for (int k0 = 0; k0 < 1024; k0 += 64) {
#pragma unroll
    for (int c = tid; c < 512; c += 256) {
      int row = c >> 3, cc = c & 7;
      *(uint4v*)&As[row][cc * 8] = *(const uint4v*)&A[(size_t)(m0 + row) * 1024 + k0 + cc * 8];
      *(uint4v*)&Bs[row][cc * 8] = *(const uint4v*)&BT[(size_t)(n0 + row) * 1024 + k0 + cc * 8];
    }
    __syncthreads();
#pragma unroll
    for (int kk = 0; kk < 64; kk += 32) {
      short8 a = *(const short8*)&As[w * 16 + lr][kk + lg * 8];
#pragma unroll
      for (int f = 0; f < 4; ++f) {
        short8 b = *(const short8*)&Bs[f * 16 + lr][kk + lg * 8];
        acc[f] = __builtin_amdgcn_mfma_f32_16x16x32_bf16(a, b, acc[f], 0, 0, 0);
      }
    }
    __syncthreads();
  }
#pragma unroll
  for (int f = 0; f < 4; ++f)
#pragma unroll
    for (int r = 0; r < 4; ++r)
      C[(size_t)(m0 + w * 16 + lg * 4 + r) * 512 + n0 + f * 16 + lr] = f2bf(acc[f][r]);
}

// ---------------- flash attention: 4 independent waves, no barriers ----------------
__global__ __launch_bounds__(256) void k_attn(const unsigned short* __restrict__ Qb,
                                              const unsigned short* __restrict__ Kb,
                                              const unsigned short* __restrict__ VT,
                                              unsigned short* __restrict__ ctx) {
  __shared__ alignas(16) unsigned short Plds[4][16][72];  // per-wave P bounce
  const int tid = threadIdx.x, w = tid >> 6, l = tid & 63;
  const int lr = l & 15, lg = l >> 4;
  const int bh = blockIdx.y;
  const int qrow = blockIdx.x * 64 + w * 16;
  const unsigned short* Qh  = Qb + (size_t)bh * 131072;   // [2048][64]
  const unsigned short* Kh  = Kb + (size_t)bh * 131072;   // [2048][64]
  const unsigned short* VTh = VT + (size_t)bh * 131072;   // [64][2048]

  short8 qa0 = *(const short8*)&Qh[(size_t)(qrow + lr) * 64 + lg * 8];
  short8 qa1 = *(const short8*)&Qh[(size_t)(qrow + lr) * 64 + 32 + lg * 8];

  f32x4 O[4] = {};
  float m_i[4] = {-1e30f, -1e30f, -1e30f, -1e30f};
  float l_i[4] = {0.f, 0.f, 0.f, 0.f};

  const unsigned short* kbase = &Kh[(size_t)lr * 64 + lg * 8];
  const unsigned short* vbase = &VTh[(size_t)lr * 2048 + lg * 8];

  // preload K-tile 0 into registers
  short8 kr[8];
#pragma unroll
  for (int t = 0; t < 4; ++t) {
    kr[t * 2]     = *(const short8*)(kbase + t * 1024);
    kr[t * 2 + 1] = *(const short8*)(kbase + t * 1024 + 32);
  }

  for (int it = 0; it < 32; ++it) {
    const int k0 = it * 64;
    // ---- issue V-tile loads early (consumed after softmax) ----
    short8 vr[8];
#pragma unroll
    for (int f = 0; f < 4; ++f) {
      vr[f * 2]     = *(const short8*)(vbase + f * 32768 + k0);
      vr[f * 2 + 1] = *(const short8*)(vbase + f * 32768 + k0 + 32);
    }
    // ---- S tile [16 q x 64 k] from prefetched K regs ----
    f32x4 s[4] = {};
#pragma unroll
    for (int t = 0; t < 4; ++t) {
      s[t] = __builtin_amdgcn_mfma_f32_16x16x32_bf16(qa0, kr[t * 2],     s[t], 0, 0, 0);
      s[t] = __builtin_amdgcn_mfma_f32_16x16x32_bf16(qa1, kr[t * 2 + 1], s[t], 0, 0, 0);
    }
    // ---- issue next K-tile loads (hide under softmax) ----
    const int knext = (it < 31) ? (k0 + 64) : 0;   // wrap: always in-bounds, result unused on last
    short8 kn[8];
    {
      const unsigned short* kb2 = kbase + (size_t)knext * 64;
#pragma unroll
      for (int t = 0; t < 4; ++t) {
        kn[t * 2]     = *(const short8*)(kb2 + t * 1024);
        kn[t * 2 + 1] = *(const short8*)(kb2 + t * 1024 + 32);
      }
    }
    // ---- online softmax (row stats across the 16-lane group) ----
    float p[4][4];
#pragma unroll
    for (int r = 0; r < 4; ++r) {
      float tm = fmaxf(fmaxf(s[0][r], s[1][r]), fmaxf(s[2][r], s[3][r]));
      tm = fmaxf(tm, __shfl_xor(tm, 1));
      tm = fmaxf(tm, __shfl_xor(tm, 2));
      tm = fmaxf(tm, __shfl_xor(tm, 4));
      tm = fmaxf(tm, __shfl_xor(tm, 8));
      float mnew  = fmaxf(m_i[r], tm);
      float alpha = __expf(m_i[r] - mnew);
      float ls = 0.f;
#pragma unroll
      for (int t = 0; t < 4; ++t) { p[t][r] = __expf(s[t][r] - mnew); ls += p[t][r]; }
      ls += __shfl_xor(ls, 1);
      ls += __shfl_xor(ls, 2);
      ls += __shfl_xor(ls, 4);
      ls += __shfl_xor(ls, 8);
      l_i[r] = l_i[r] * alpha + ls;
      m_i[r] = mnew;
#pragma unroll
      for (int f = 0; f < 4; ++f) O[f][r] *= alpha;
    }
    // ---- P (C-layout) -> per-wave LDS -> A-layout fragments (wave-local, no barrier) ----
#pragma unroll
    for (int t = 0; t < 4; ++t)
#pragma unroll
      for (int r = 0; r < 4; ++r)
        Plds[w][lg * 4 + r][t * 16 + lr] = f2bf(p[t][r]);
    asm volatile("s_waitcnt lgkmcnt(0)" ::: "memory");
    __builtin_amdgcn_sched_barrier(0);
    short8 pa0 = *(const short8*)&Plds[w][lr][lg * 8];
    short8 pa1 = *(const short8*)&Plds[w][lr][32 + lg * 8];
    // ---- O += P @ V ----
#pragma unroll
    for (int f = 0; f < 4; ++f) {
      O[f] = __builtin_amdgcn_mfma_f32_16x16x32_bf16(pa0, vr[f * 2],     O[f], 0, 0, 0);
      O[f] = __builtin_amdgcn_mfma_f32_16x16x32_bf16(pa1, vr[f * 2 + 1], O[f], 0, 0, 0);
    }
    // ---- rotate K double-buffer ----
#pragma unroll
    for (int i = 0; i < 8; ++i) kr[i] = kn[i];
  }
#pragma unroll
  for (int f = 0; f < 4; ++f)
#pragma unroll
    for (int r = 0; r < 4; ++r) {
      float val = O[f][r] * (0.125f / l_i[r]);   // post-softmax /8 + normalization
      ctx[(size_t)(bh * 2048 + qrow + lg * 4 + r) * 64 + f * 16 + lr] = f2bf(val);
    }
}

// ------- out projection: OUT[32768,1024] f32 = ctx[32768,64] @ Wo + bo -------
__global__ __launch_bounds__(256) void k_gemmo(const unsigned short* __restrict__ A,
                                               const unsigned short* __restrict__ BT,  // WoT[1024][64]
                                               const float* __restrict__ bias,
                                               float* __restrict__ C) {
  __shared__ alignas(16) unsigned short As[64][72];
  __shared__ alignas(16) unsigned short Bs[64][72];
  const int tid = threadIdx.x, w = tid >> 6, l = tid & 63;
  const int lr = l & 15, lg = l >> 4;
  const int m0 = blockIdx.x * 64, n0 = blockIdx.y * 64;
#pragma unroll
  for (int c = tid; c < 512; c += 256) {
    int row = c >> 3, cc = c & 7;
    *(uint4v*)&As[row][cc * 8] = *(const uint4v*)&A[(size_t)(m0 + row) * 64 + cc * 8];
    *(uint4v*)&Bs[row][cc * 8] = *(const uint4v*)&BT[(size_t)(n0 + row) * 64 + cc * 8];
  }
  __syncthreads();
  f32x4 acc[4] = {};
#pragma unroll
  for (int kk = 0; kk < 64; kk += 32) {
    short8 a = *(const short8*)&As[w * 16 + lr][kk + lg * 8];
#pragma unroll
    for (int f = 0; f < 4; ++f) {
      short8 b = *(const short8*)&Bs[f * 16 + lr][kk + lg * 8];
      acc[f] = __builtin_amdgcn_mfma_f32_16x16x32_bf16(a, b, acc[f], 0, 0, 0);
    }
  }
#pragma unroll
  for (int f = 0; f < 4; ++f)
#pragma unroll
    for (int r = 0; r < 4; ++r) {
      int col = n0 + f * 16 + lr;
      C[(size_t)(m0 + w * 16 + lg * 4 + r) * 1024 + col] = acc[f][r] + bias[col];
    }
}

extern "C" void kernel_launch(void* const* d_in, const int* in_sizes, int n_in,
                              void* d_out, int out_size, void* d_ws, size_t ws_size,
                              hipStream_t stream) {
  const float* X  = (const float*)d_in[0];
  const float* Wq = (const float*)d_in[1];
  const float* Wk = (const float*)d_in[2];
  const float* Wv = (const float*)d_in[3];
  const float* Wo = (const float*)d_in[4];
  const float* bo = (const float*)d_in[5];
  float* out = (float*)d_out;

  char* ws = (char*)d_ws;
  unsigned short* Xb    = (unsigned short*)ws; ws += 8388608;   // [4096,1024] bf16
  unsigned short* WqkvT = (unsigned short*)ws; ws += 3145728;   // [3][512][1024] bf16
  unsigned short* WoT   = (unsigned short*)ws; ws += 131072;    // [1024,64] bf16
  unsigned short* Qb    = (unsigned short*)ws; ws += 4194304;   // [4096,512]
  unsigned short* Kb    = (unsigned short*)ws; ws += 4194304;
  unsigned short* Vb    = (unsigned short*)ws; ws += 4194304;
  unsigned short* VT    = (unsigned short*)ws; ws += 4194304;   // [16][64][2048]
  unsigned short* Cx    = (unsigned short*)ws; ws += 4194304;   // [32768,64]

  k_cvt<<<4096, 256, 0, stream>>>(X, Xb, 1048576);
  k_twtT<<<dim3(16, 8), 256, 0, stream>>>(Wq, WqkvT,           1024, 512);
  k_twtT<<<dim3(16, 8), 256, 0, stream>>>(Wk, WqkvT + 524288,  1024, 512);
  k_twtT<<<dim3(16, 8), 256, 0, stream>>>(Wv, WqkvT + 1048576, 1024, 512);
  k_twtT<<<dim3(1, 16), 256, 0, stream>>>(Wo, WoT, 64, 1024);

  k_gemmqkv<<<dim3(64, 24), 256, 0, stream>>>(Xb, WqkvT, Qb, Kb, Vb);

  k_tv<<<dim3(32, 16), 256, 0, stream>>>(Vb, VT);
  k_attn<<<dim3(32, 16), 256, 0, stream>>>(Qb, Kb, VT, Cx);
  k_gemmo<<<dim3(512, 16), 256, 0, stream>>>(Cx, WoT, bo, out);
}

// Round 3
// 308.144 us; speedup vs baseline: 1.2138x; 1.0290x over previous
//
#include <hip/hip_runtime.h>

// B=2, S=2048, IN_F=1024, HEADS=8, DPH=64, OUT_F=1024.
// Quirk: reshape is a raw view -> per (b,h) the Q/K/V matrices are CONTIGUOUS
// [2048,64] slabs of the [4096,512] projection output at offset bh*131072.
// Quirk: no pre-softmax scale; divide by 8 AFTER softmax (folded into O epilogue).
//
// Attention uses SWAPPED operands: S^T = mfma(K,Q) so each lane owns one q-row
// (q = lane&15) -> softmax row-reduce is in-lane + 2 shfl_xor; PV computes
// O^T = mfma(VT,P) so alpha/1/l are per-lane scalars (no cross-lane at all).

using short8  = __attribute__((ext_vector_type(8))) short;
using short4v = __attribute__((ext_vector_type(4))) short;
using f32x4   = __attribute__((ext_vector_type(4))) float;
using float4v = __attribute__((ext_vector_type(4))) float;
using uint4v  = __attribute__((ext_vector_type(4))) unsigned int;

__device__ __forceinline__ unsigned short f2bf(float x) {
  unsigned int u = __float_as_uint(x);
  u += 0x7FFFu + ((u >> 16) & 1u);          // round-to-nearest-even
  return (unsigned short)(u >> 16);
}

#define GLD_LDS16(g, s)                                                              \
  __builtin_amdgcn_global_load_lds((const __attribute__((address_space(1))) unsigned int*)(g), \
                                   (__attribute__((address_space(3))) unsigned int*)(s), 16, 0, 0)

// ---------------- f32 -> bf16 convert (4 elems/thread) ----------------
__global__ __launch_bounds__(256) void k_cvt(const float* __restrict__ in,
                                             unsigned short* __restrict__ out,
                                             int n4) {
  int id = blockIdx.x * 256 + threadIdx.x;
  if (id >= n4) return;
  float4v v = *(const float4v*)(in + (size_t)id * 4);
  short4v o;
#pragma unroll
  for (int i = 0; i < 4; ++i) o[i] = (short)f2bf(v[i]);
  *(short4v*)(out + (size_t)id * 4) = o;
}

// ---- {Wq,Wk,Wv}[1024,512] f32 -> WT[3][512][1024] bf16, LDS-tiled ----
__global__ __launch_bounds__(256) void k_twt3(const float* __restrict__ Wq,
                                              const float* __restrict__ Wk,
                                              const float* __restrict__ Wv,
                                              unsigned short* __restrict__ WT) {
  __shared__ alignas(16) unsigned short t[64][72];
  const int z = blockIdx.z;
  const float* W = (z == 0) ? Wq : (z == 1) ? Wk : Wv;
  unsigned short* dst0 = WT + (size_t)z * 524288;
  const int k0 = blockIdx.x * 64, n0 = blockIdx.y * 64;
  const int kk = threadIdx.x & 63, g = (threadIdx.x >> 6) * 16;
  const float* src = W + (size_t)(k0 + kk) * 512 + n0 + g;
#pragma unroll
  for (int j4 = 0; j4 < 4; ++j4) {
    float4v v = *(const float4v*)(src + j4 * 4);
#pragma unroll
    for (int i = 0; i < 4; ++i) t[g + j4 * 4 + i][kk] = f2bf(v[i]);
  }
  __syncthreads();
  const int nn = threadIdx.x >> 2, kg = (threadIdx.x & 3) * 16;
  short8 o0, o1;
#pragma unroll
  for (int j = 0; j < 8; ++j) { o0[j] = t[nn][kg + j]; o1[j] = t[nn][kg + 8 + j]; }
  unsigned short* dst = dst0 + (size_t)(n0 + nn) * 1024 + k0 + kg;
  *(short8*)dst = o0;
  *(short8*)(dst + 8) = o1;
}

// ---- Wo[64,1024] f32 -> WoT[1024,64] bf16 ----
__global__ __launch_bounds__(256) void k_twtO(const float* __restrict__ W,
                                              unsigned short* __restrict__ WT) {
  __shared__ alignas(16) unsigned short t[64][72];
  const int n0 = blockIdx.y * 64;
  const int kk = threadIdx.x & 63, g = (threadIdx.x >> 6) * 16;
  const float* src = W + (size_t)kk * 1024 + n0 + g;
#pragma unroll
  for (int j4 = 0; j4 < 4; ++j4) {
    float4v v = *(const float4v*)(src + j4 * 4);
#pragma unroll
    for (int i = 0; i < 4; ++i) t[g + j4 * 4 + i][kk] = f2bf(v[i]);
  }
  __syncthreads();
  const int nn = threadIdx.x >> 2, kg = (threadIdx.x & 3) * 16;
  short8 o0, o1;
#pragma unroll
  for (int j = 0; j < 8; ++j) { o0[j] = t[nn][kg + j]; o1[j] = t[nn][kg + 8 + j]; }
  unsigned short* dst = WT + (size_t)(n0 + nn) * 64 + kg;
  *(short8*)dst = o0;
  *(short8*)(dst + 8) = o1;
}

// -------- V slab [2048,64] -> VT[bh][64][2048], LDS-tiled --------
__global__ __launch_bounds__(256) void k_tv(const unsigned short* __restrict__ Vb,
                                            unsigned short* __restrict__ VT) {
  __shared__ alignas(16) unsigned short t[64][72];
  const int bh = blockIdx.y, r0 = blockIdx.x * 64;
  const int rr = threadIdx.x & 63, g = (threadIdx.x >> 6) * 16;
  const unsigned short* src = Vb + (size_t)bh * 131072 + (size_t)(r0 + rr) * 64 + g;
  short8 a = *(const short8*)src;
  short8 b = *(const short8*)(src + 8);
#pragma unroll
  for (int j = 0; j < 8; ++j) { t[g + j][rr] = a[j]; t[g + 8 + j][rr] = b[j]; }
  __syncthreads();
  const int d = threadIdx.x >> 2, rg = (threadIdx.x & 3) * 16;
  short8 o0, o1;
#pragma unroll
  for (int j = 0; j < 8; ++j) { o0[j] = t[d][rg + j]; o1[j] = t[d][rg + 8 + j]; }
  unsigned short* dst = VT + (size_t)(bh * 64 + d) * 2048 + r0 + rg;
  *(short8*)dst = o0;
  *(short8*)(dst + 8) = o1;
}

// ------- fused QKV GEMM, m97 structure: 128x128 tile, global_load_lds staging -------
// C[4096][1536] = Xb[4096][1024] @ WqkvT[1536][1024]^T, scattered to Q/K/V [4096][512].
__global__ __launch_bounds__(256) void k_gemmqkv(const unsigned short* __restrict__ A,
                                                 const unsigned short* __restrict__ WT,
                                                 unsigned short* __restrict__ Q,
                                                 unsigned short* __restrict__ K_,
                                                 unsigned short* __restrict__ V_) {
  __shared__ alignas(16) unsigned short As[128 * 64];   // 16 KB, linear row-major [128][64]
  __shared__ alignas(16) unsigned short Bs[128 * 64];
  const int tid = threadIdx.x, w = tid >> 6, l = tid & 63;
  const int lr = l & 15, lg = l >> 4;
  const int m0 = blockIdx.x * 128, n0 = blockIdx.y * 128;
  const int wr = w >> 1, wc = w & 1;
  f32x4 acc[4][4] = {};
  const int srow = w * 8 + (l >> 3);            // staging row (+ i*32)
  const int scol = (l & 7) * 8;
  const unsigned short* ga = A  + (size_t)(m0 + srow) * 1024 + scol;
  const unsigned short* gb = WT + (size_t)(n0 + srow) * 1024 + scol;

  for (int k0 = 0; k0 < 1024; k0 += 64) {
#pragma unroll
    for (int i = 0; i < 4; ++i) {
      GLD_LDS16(ga + (size_t)i * 32768 + k0, As + (i * 32 + w * 8) * 64);
      GLD_LDS16(gb + (size_t)i * 32768 + k0, Bs + (i * 32 + w * 8) * 64);
    }
    asm volatile("s_waitcnt vmcnt(0)" ::: "memory");
    __syncthreads();
#pragma unroll
    for (int kk = 0; kk < 2; ++kk) {
      short8 a[4], b[4];
#pragma unroll
      for (int mi = 0; mi < 4; ++mi)
        a[mi] = *(const short8*)&As[(wr * 64 + mi * 16 + lr) * 64 + kk * 32 + lg * 8];
#pragma unroll
      for (int ni = 0; ni < 4; ++ni)
        b[ni] = *(const short8*)&Bs[(wc * 64 + ni * 16 + lr) * 64 + kk * 32 + lg * 8];
#pragma unroll
      for (int mi = 0; mi < 4; ++mi)
#pragma unroll
        for (int ni = 0; ni < 4; ++ni)
          acc[mi][ni] = __builtin_amdgcn_mfma_f32_16x16x32_bf16(a[mi], b[ni], acc[mi][ni], 0, 0, 0);
    }
    __syncthreads();
  }
  const int which = blockIdx.y >> 2;            // 128-blocks align to 512-boundaries
  unsigned short* C = (which == 0) ? Q : (which == 1) ? K_ : V_;
  const int cbase = (blockIdx.y & 3) * 128 + wc * 64;
#pragma unroll
  for (int mi = 0; mi < 4; ++mi)
#pragma unroll
    for (int ni = 0; ni < 4; ++ni) {
      int row = m0 + wr * 64 + mi * 16 + lg * 4;
      int col = cbase + ni * 16 + lr;
#pragma unroll
      for (int r = 0; r < 4; ++r)
        C[(size_t)(row + r) * 512 + col] = f2bf(acc[mi][ni][r]);
    }
}

// ---------------- flash attention, swapped-operand structure ----------------
__global__ __launch_bounds__(256) void k_attn(const unsigned short* __restrict__ Qb,
                                              const unsigned short* __restrict__ Kb,
                                              const unsigned short* __restrict__ VT,
                                              unsigned short* __restrict__ ctx) {
  __shared__ alignas(16) unsigned short Plds[4][16][72];  // per-wave P bounce
  const int tid = threadIdx.x, w = tid >> 6, l = tid & 63;
  const int lr = l & 15, lg = l >> 4;
  const int bh = blockIdx.y;
  const int qrow = blockIdx.x * 64 + w * 16;
  const unsigned short* Qh  = Qb + (size_t)bh * 131072;   // [2048][64]
  const unsigned short* Kh  = Kb + (size_t)bh * 131072;   // [2048][64]
  const unsigned short* VTh = VT + (size_t)bh * 131072;   // [64][2048]

  // Q as B-fragment: lane holds Q[qrow+lr][lg*8..+7]
  short8 qb0 = *(const short8*)&Qh[(size_t)(qrow + lr) * 64 + lg * 8];
  short8 qb1 = *(const short8*)&Qh[(size_t)(qrow + lr) * 64 + 32 + lg * 8];

  f32x4 O[4] = {};          // O^T: lane holds ctx[q=qrow+lr][d=f*16+lg*4+r]
  float m_i = -1e30f, l_i = 0.f;   // per-lane: q = qrow + lr

  const unsigned short* kbase = &Kh[(size_t)lr * 64 + lg * 8];
  const unsigned short* vbase = &VTh[(size_t)lr * 2048 + lg * 8];

  short8 kr[8];             // K A-fragments for current tile
#pragma unroll
  for (int t = 0; t < 4; ++t) {
    kr[t * 2]     = *(const short8*)(kbase + t * 1024);
    kr[t * 2 + 1] = *(const short8*)(kbase + t * 1024 + 32);
  }

  for (int it = 0; it < 32; ++it) {
    const int k0 = it * 64;
    // V A-fragments issued early (consumed after softmax)
    short8 vr[8];
#pragma unroll
    for (int f = 0; f < 4; ++f) {
      vr[f * 2]     = *(const short8*)(vbase + f * 32768 + k0);
      vr[f * 2 + 1] = *(const short8*)(vbase + f * 32768 + k0 + 32);
    }
    // S^T tile: s[t][r] = S[k = k0+t*16+lg*4+r][q = qrow+lr]
    f32x4 s[4] = {};
#pragma unroll
    for (int t = 0; t < 4; ++t) {
      s[t] = __builtin_amdgcn_mfma_f32_16x16x32_bf16(kr[t * 2],     qb0, s[t], 0, 0, 0);
      s[t] = __builtin_amdgcn_mfma_f32_16x16x32_bf16(kr[t * 2 + 1], qb1, s[t], 0, 0, 0);
    }
    // prefetch next K-tile (hidden under softmax)
    const int knext = (it < 31) ? (k0 + 64) : 0;
    short8 kn[8];
    {
      const unsigned short* kb2 = kbase + (size_t)knext * 64;
#pragma unroll
      for (int t = 0; t < 4; ++t) {
        kn[t * 2]     = *(const short8*)(kb2 + t * 1024);
        kn[t * 2 + 1] = *(const short8*)(kb2 + t * 1024 + 32);
      }
    }
    // ---- softmax: in-lane over 16 values + 2 shfl_xor across lg groups ----
    float t0 = fmaxf(fmaxf(s[0][0], s[0][1]), fmaxf(s[0][2], s[0][3]));
    float t1 = fmaxf(fmaxf(s[1][0], s[1][1]), fmaxf(s[1][2], s[1][3]));
    float t2 = fmaxf(fmaxf(s[2][0], s[2][1]), fmaxf(s[2][2], s[2][3]));
    float t3 = fmaxf(fmaxf(s[3][0], s[3][1]), fmaxf(s[3][2], s[3][3]));
    float tmax = fmaxf(fmaxf(t0, t1), fmaxf(t2, t3));
    tmax = fmaxf(tmax, __shfl_xor(tmax, 16));
    tmax = fmaxf(tmax, __shfl_xor(tmax, 32));
    float mnew  = fmaxf(m_i, tmax);
    float alpha = __expf(m_i - mnew);
    float p[4][4];
#pragma unroll
    for (int t = 0; t < 4; ++t)
#pragma unroll
      for (int r = 0; r < 4; ++r) p[t][r] = __expf(s[t][r] - mnew);
    float u0 = (p[0][0] + p[0][1]) + (p[0][2] + p[0][3]);
    float u1 = (p[1][0] + p[1][1]) + (p[1][2] + p[1][3]);
    float u2 = (p[2][0] + p[2][1]) + (p[2][2] + p[2][3]);
    float u3 = (p[3][0] + p[3][1]) + (p[3][2] + p[3][3]);
    float ls = (u0 + u1) + (u2 + u3);
    ls += __shfl_xor(ls, 16);
    ls += __shfl_xor(ls, 32);
    l_i = l_i * alpha + ls;
    m_i = mnew;
#pragma unroll
    for (int f = 0; f < 4; ++f) O[f] *= alpha;   // per-lane scalar, no shfl
    // ---- P -> wave-local LDS bounce into B-fragment layout ----
#pragma unroll
    for (int t = 0; t < 4; ++t) {
      short4v pk;
#pragma unroll
      for (int r = 0; r < 4; ++r) pk[r] = (short)f2bf(p[t][r]);
      *(short4v*)&Plds[w][lr][t * 16 + lg * 4] = pk;   // P[q=lr][k=t*16+lg*4..+3]
    }
    asm volatile("s_waitcnt lgkmcnt(0)" ::: "memory");
    __builtin_amdgcn_sched_barrier(0);
    short8 pb0 = *(const short8*)&Plds[w][lr][lg * 8];        // P[q=lr][lg*8..+7]
    short8 pb1 = *(const short8*)&Plds[w][lr][32 + lg * 8];
    // ---- O^T += VT-frag @ P-frag ----
#pragma unroll
    for (int f = 0; f < 4; ++f) {
      O[f] = __builtin_amdgcn_mfma_f32_16x16x32_bf16(vr[f * 2],     pb0, O[f], 0, 0, 0);
      O[f] = __builtin_amdgcn_mfma_f32_16x16x32_bf16(vr[f * 2 + 1], pb1, O[f], 0, 0, 0);
    }
#pragma unroll
    for (int i = 0; i < 8; ++i) kr[i] = kn[i];
  }
  // epilogue: per-lane scale, packed b64 stores
  const float scale = 0.125f / l_i;
  unsigned short* base = ctx + (size_t)(bh * 2048 + qrow + lr) * 64;
#pragma unroll
  for (int f = 0; f < 4; ++f) {
    short4v o;
#pragma unroll
    for (int r = 0; r < 4; ++r) o[r] = (short)f2bf(O[f][r] * scale);
    *(short4v*)(base + f * 16 + lg * 4) = o;
  }
}

// ------- out projection, 128x128 tile: OUT[32768,1024] f32 = ctx[32768,64] @ WoT^T + bo -------
__global__ __launch_bounds__(256) void k_gemmo(const unsigned short* __restrict__ A,
                                               const unsigned short* __restrict__ BT,  // WoT[1024][64]
                                               const float* __restrict__ bias,
                                               float* __restrict__ C) {
  __shared__ alignas(16) unsigned short As[128 * 64];
  __shared__ alignas(16) unsigned short Bs[128 * 64];
  const int tid = threadIdx.x, w = tid >> 6, l = tid & 63;
  const int lr = l & 15, lg = l >> 4;
  const int m0 = blockIdx.x * 128, n0 = blockIdx.y * 128;
  const int wr = w >> 1, wc = w & 1;
  const int srow = w * 8 + (l >> 3);
  const int scol = (l & 7) * 8;
  const unsigned short* ga = A  + (size_t)(m0 + srow) * 64 + scol;
  const unsigned short* gb = BT + (size_t)(n0 + srow) * 64 + scol;
#pragma unroll
  for (int i = 0; i < 4; ++i) {
    GLD_LDS16(ga + (size_t)i * 2048, As + (i * 32 + w * 8) * 64);
    GLD_LDS16(gb + (size_t)i * 2048, Bs + (i * 32 + w * 8) * 64);
  }
  asm volatile("s_waitcnt vmcnt(0)" ::: "memory");
  __syncthreads();
  f32x4 acc[4][4] = {};
#pragma unroll
  for (int kk = 0; kk < 2; ++kk) {
    short8 a[4], b[4];
#pragma unroll
    for (int mi = 0; mi < 4; ++mi)
      a[mi] = *(const short8*)&As[(wr * 64 + mi * 16 + lr) * 64 + kk * 32 + lg * 8];
#pragma unroll
    for (int ni = 0; ni < 4; ++ni)
      b[ni] = *(const short8*)&Bs[(wc * 64 + ni * 16 + lr) * 64 + kk * 32 + lg * 8];
#pragma unroll
    for (int mi = 0; mi < 4; ++mi)
#pragma unroll
      for (int ni = 0; ni < 4; ++ni)
        acc[mi][ni] = __builtin_amdgcn_mfma_f32_16x16x32_bf16(a[mi], b[ni], acc[mi][ni], 0, 0, 0);
  }
  float bv[4];
#pragma unroll
  for (int ni = 0; ni < 4; ++ni) bv[ni] = bias[n0 + wc * 64 + ni * 16 + lr];
#pragma unroll
  for (int mi = 0; mi < 4; ++mi)
#pragma unroll
    for (int ni = 0; ni < 4; ++ni) {
      int row = m0 + wr * 64 + mi * 16 + lg * 4;
      int col = n0 + wc * 64 + ni * 16 + lr;
#pragma unroll
      for (int r = 0; r < 4; ++r)
        C[(size_t)(row + r) * 1024 + col] = acc[mi][ni][r] + bv[ni];
    }
}

extern "C" void kernel_launch(void* const* d_in, const int* in_sizes, int n_in,
                              void* d_out, int out_size, void* d_ws, size_t ws_size,
                              hipStream_t stream) {
  const float* X  = (const float*)d_in[0];
  const float* Wq = (const float*)d_in[1];
  const float* Wk = (const float*)d_in[2];
  const float* Wv = (const float*)d_in[3];
  const float* Wo = (const float*)d_in[4];
  const float* bo = (const float*)d_in[5];
  float* out = (float*)d_out;

  char* ws = (char*)d_ws;
  unsigned short* Xb    = (unsigned short*)ws; ws += 8388608;   // [4096,1024] bf16
  unsigned short* WqkvT = (unsigned short*)ws; ws += 3145728;   // [3][512][1024] bf16
  unsigned short* WoT   = (unsigned short*)ws; ws += 131072;    // [1024,64] bf16
  unsigned short* Qb    = (unsigned short*)ws; ws += 4194304;   // [4096,512]
  unsigned short* Kb    = (unsigned short*)ws; ws += 4194304;
  unsigned short* Vb    = (unsigned short*)ws; ws += 4194304;
  unsigned short* VT    = (unsigned short*)ws; ws += 4194304;   // [16][64][2048]
  unsigned short* Cx    = (unsigned short*)ws; ws += 4194304;   // [32768,64]

  k_cvt<<<4096, 256, 0, stream>>>(X, Xb, 1048576);
  k_twt3<<<dim3(16, 8, 3), 256, 0, stream>>>(Wq, Wk, Wv, WqkvT);
  k_twtO<<<dim3(1, 16), 256, 0, stream>>>(Wo, WoT);

  k_gemmqkv<<<dim3(32, 12), 256, 0, stream>>>(Xb, WqkvT, Qb, Kb, Vb);

  k_tv<<<dim3(32, 16), 256, 0, stream>>>(Vb, VT);
  k_attn<<<dim3(32, 16), 256, 0, stream>>>(Qb, Kb, VT, Cx);
  k_gemmo<<<dim3(256, 8), 256, 0, stream>>>(Cx, WoT, bo, out);
}